// Round 6
// baseline (134.179 us; speedup 1.0000x reference)
//
#include <hip/hip_runtime.h>
#include <hip/hip_bf16.h>

// PQ embedding gather:
//   out[t, m*32 + j] = centroids[m, item_codes[ids[t], m], j]
// B*S = 102400 tokens, M = 8 code bytes, SUB = 32 floats, 256 centroids/byte.
//   ids:       int32   [B*S]
//   item_codes:int32   [(N+1)*8]    (32 MB, random-row gather)
//   centroids: float32 [8*256*32]   (256 KB)
//   out:       float32 [B*S*256]    (105 MB, streaming write -> nontemporal)
//
// 64 tokens / 256-thread block.
//   Phase A: 2 independent random code-row gathers per thread -> LDS (nt loads,
//            zero reuse within dispatch, don't evict centroids from L2).
//   Phase B: each wave writes 16 tokens; unroll x8 -> 8 independent
//            centroid-gather/store chains per thread; nontemporal stores.
//
// NOTE: __builtin_nontemporal_* needs clang ext-vector types, not HIP float4.

typedef float f4 __attribute__((ext_vector_type(4)));

#define M_BYTES 8
#define SUB_DIM 32
#define EMB     (M_BYTES * SUB_DIM)   // 256 floats per token
#define TOK_PER_BLOCK 64
#define BLOCK 256

__global__ __launch_bounds__(BLOCK) void ItemCodeLayer_30253749633338_kernel(
    const int*   __restrict__ ids,    // [B*S]
    const int*   __restrict__ codes,  // [(N+1)*M]
    const float* __restrict__ cent,   // [M*256*SUB]
    float*       __restrict__ out,    // [B*S*EMB]
    int n_tokens)
{
    __shared__ int s_codes[TOK_PER_BLOCK * M_BYTES];   // 2 KB

    const int tid  = threadIdx.x;
    const int base = blockIdx.x * TOK_PER_BLOCK;

    // ---- Phase A: gather code rows for 64 tokens (2 independent chains/thread)
    const int t0 = tid >> 3;          // 0..31
    const int m  = tid & 7;           // 0..7
    const int t1 = t0 + 32;           // 32..63

    int id0 = (base + t0 < n_tokens) ? ids[base + t0] : 0;
    int id1 = (base + t1 < n_tokens) ? ids[base + t1] : 0;

    // Random 32 B rows from the 32 MB table; no reuse -> nontemporal.
    int c0 = __builtin_nontemporal_load(codes + (size_t)id0 * M_BYTES + m);
    int c1 = __builtin_nontemporal_load(codes + (size_t)id1 * M_BYTES + m);
    s_codes[t0 * M_BYTES + m] = c0;
    s_codes[t1 * M_BYTES + m] = c1;
    __syncthreads();

    // ---- Phase B: each wave streams 16 tokens (1 KB per token), unroll x8
    const int wave = tid >> 6;        // 0..3
    const int l    = tid & 63;
    const int lm   = l >> 3;          // code byte handled by this lane
    const int lj   = (l & 7) * 4;     // float offset within sub-embedding

    #pragma unroll
    for (int it = 0; it < 16; it += 8) {
        int tk[8];
        f4  v[8];
        #pragma unroll
        for (int u = 0; u < 8; ++u) {
            tk[u] = (it + u) * 4 + wave;                 // 0..63, disjoint per wave
            int code = s_codes[tk[u] * M_BYTES + lm];    // LDS broadcast (8 lanes/addr)
            v[u] = *reinterpret_cast<const f4*>(
                cent + ((size_t)(lm * 256 + code) * SUB_DIM + lj));
        }
        #pragma unroll
        for (int u = 0; u < 8; ++u) {
            int t = base + tk[u];
            if (t < n_tokens) {
                // 64 lanes -> contiguous 1 KB nontemporal store
                f4* dst = reinterpret_cast<f4*>(
                    out + ((size_t)t * EMB + lm * SUB_DIM + lj));
                __builtin_nontemporal_store(v[u], dst);
            }
        }
    }
}

extern "C" void kernel_launch(void* const* d_in, const int* in_sizes, int n_in,
                              void* d_out, int out_size, void* d_ws, size_t ws_size,
                              hipStream_t stream) {
    const int*   ids   = (const int*)  d_in[0];   // input_ids  [B*S] int32
    const int*   codes = (const int*)  d_in[1];   // item_codes [(N+1)*M] int32
    const float* cent  = (const float*)d_in[2];   // centroids  [M*256*SUB] float32
    float*       out   = (float*)      d_out;

    const int n_tokens = in_sizes[0];             // 102400 tokens
    const int grid = (n_tokens + TOK_PER_BLOCK - 1) / TOK_PER_BLOCK;   // 1600

    hipLaunchKernelGGL(ItemCodeLayer_30253749633338_kernel,
                       dim3(grid), dim3(BLOCK), 0, stream,
                       ids, codes, cent, out, n_tokens);
}

// Round 7
// 128.682 us; speedup vs baseline: 1.0427x; 1.0427x over previous
//
#include <hip/hip_runtime.h>
#include <hip/hip_bf16.h>

// PQ embedding gather:
//   out[t, m*32 + j] = centroids[m, item_codes[ids[t], m], j]
// B*S = 102400 tokens, M = 8 code bytes, SUB = 32 floats, 256 centroids/byte.
//   ids:       int32   [B*S]
//   item_codes:int32   [(N+1)*8]    (32 MB, random-row gather -> latency hazard)
//   centroids: float32 [8*256*32]   (256 KB)
//   out:       float32 [B*S*256]    (105 MB, streaming coalesced write)
//
// 128 tokens / 256-thread block (grid 800).
//   Phase A: each thread issues ONE independent 16 B (dwordx4) nontemporal
//            load = half a code row; 128 random lines in flight per block.
//            (R6 post-mortem: nt *stores* regressed -> reverted; nt loads on
//            the zero-reuse code rows kept so they don't evict centroids.)
//   Phase B: each wave writes 32 tokens (1 KB each), unroll x8 independent
//            centroid-gather/store chains; plain (cached) stores.

typedef float f4  __attribute__((ext_vector_type(4)));
typedef int   v4i __attribute__((ext_vector_type(4)));

#define M_BYTES 8
#define SUB_DIM 32
#define EMB     (M_BYTES * SUB_DIM)   // 256 floats per token
#define TOK_PER_BLOCK 128
#define BLOCK 256

__global__ __launch_bounds__(BLOCK) void ItemCodeLayer_30253749633338_kernel(
    const int*   __restrict__ ids,    // [B*S]
    const int*   __restrict__ codes,  // [(N+1)*M]
    const float* __restrict__ cent,   // [M*256*SUB]
    float*       __restrict__ out,    // [B*S*EMB]
    int n_tokens)
{
    __shared__ int s_codes[TOK_PER_BLOCK * M_BYTES];   // 4 KB

    const int tid  = threadIdx.x;
    const int base = blockIdx.x * TOK_PER_BLOCK;

    // ---- Phase A: 128 code rows, one independent 16 B chunk per thread.
    {
        const int tA = tid >> 1;          // 0..127 : token within block
        const int h  = tid & 1;           // 0/1    : which 16 B half of the 32 B row
        int id = (base + tA < n_tokens) ? ids[base + tA] : 0;   // 2 lanes share id line
        // Random 32 B rows in the 32 MB table; zero reuse -> nontemporal load.
        v4i row = __builtin_nontemporal_load(
            reinterpret_cast<const v4i*>(codes + (size_t)id * M_BYTES + h * 4));
        *reinterpret_cast<v4i*>(&s_codes[tA * M_BYTES + h * 4]) = row;
    }
    __syncthreads();

    // ---- Phase B: each wave streams 32 tokens (1 KB per token), unroll x8.
    const int wave = tid >> 6;            // 0..3
    const int l    = tid & 63;
    const int lm   = l >> 3;              // code byte handled by this lane
    const int lj   = (l & 7) * 4;         // float offset within sub-embedding
    const float* centBase = cent + (size_t)lm * 256 * SUB_DIM + lj;

    #pragma unroll
    for (int it = 0; it < 32; it += 8) {
        int tk[8];
        f4  v[8];
        #pragma unroll
        for (int u = 0; u < 8; ++u) {
            tk[u] = wave * 32 + it + u;                  // 0..127, disjoint per wave
            int code = s_codes[tk[u] * M_BYTES + lm];    // LDS broadcast (8 lanes/addr)
            v[u] = *reinterpret_cast<const f4*>(centBase + (size_t)code * SUB_DIM);
        }
        #pragma unroll
        for (int u = 0; u < 8; ++u) {
            int t = base + tk[u];
            if (t < n_tokens) {
                // 64 lanes -> contiguous 1 KB cached store
                *reinterpret_cast<f4*>(
                    out + ((size_t)t * EMB + lm * SUB_DIM + lj)) = v[u];
            }
        }
    }
}

extern "C" void kernel_launch(void* const* d_in, const int* in_sizes, int n_in,
                              void* d_out, int out_size, void* d_ws, size_t ws_size,
                              hipStream_t stream) {
    const int*   ids   = (const int*)  d_in[0];   // input_ids  [B*S] int32
    const int*   codes = (const int*)  d_in[1];   // item_codes [(N+1)*M] int32
    const float* cent  = (const float*)d_in[2];   // centroids  [M*256*SUB] float32
    float*       out   = (float*)      d_out;

    const int n_tokens = in_sizes[0];             // 102400 tokens
    const int grid = (n_tokens + TOK_PER_BLOCK - 1) / TOK_PER_BLOCK;   // 800

    hipLaunchKernelGGL(ItemCodeLayer_30253749633338_kernel,
                       dim3(grid), dim3(BLOCK), 0, stream,
                       ids, codes, cent, out, n_tokens);
}